// Round 1
// baseline (502.423 us; speedup 1.0000x reference)
//
#include <hip/hip_runtime.h>
#include <hip/hip_bf16.h>
#include <math.h>

typedef __bf16 bf16_t;
typedef bf16_t bf16x8 __attribute__((ext_vector_type(8)));
typedef bf16_t bf16x4 __attribute__((ext_vector_type(4)));
typedef float  f32x4  __attribute__((ext_vector_type(4)));

#define D_IN   512
#define DMODEL 1024
#define SEQ    2048
#define BATCH  8
#define NTOK   (BATCH*SEQ)

typedef __attribute__((address_space(1))) unsigned int gu32;
typedef __attribute__((address_space(3))) unsigned int lu32;

__device__ __forceinline__ void async16(const void* g, void* l) {
    __builtin_amdgcn_global_load_lds((gu32*)g, (lu32*)l, 16, 0, 0);
}

// ---------------------------------------------------------------------------
// Unified bf16 GEMM: C[M,N] = A[M,K] * B[N,K]^T  (both row-major over K)
// R13: 256x256 tile, 8-wave (512 thr), BK=64, 2 K-tiles/iter, 8-phase
// schedule with counted vmcnt (T3+T4) + setprio around MFMA (T5).
// Each phase: {12x ds_read_b128 (one C-quadrant) || stage 1 region
// (2x global_load_lds x16B/wave)} -> s_barrier -> lgkmcnt(0) -> 16 MFMA
// -> s_barrier.  Regions: A split by qm rows ([0,64)u[128,192) vs rest),
// B split by qn rows; tile X staged in phases (X-2,3),(X-2,4),(X-1,1),
// (X-1,2) — each region staged exactly one phase after its last read
// (barrier-separated), confirmed by vmcnt(4) at phases 4/8 one phase
// before its first read. Never vmcnt(0) in steady state.
// Swizzle: 16B chunk phys = logical ^ (row&7) (0 bank conflicts since R3);
// staging pre-swizzles the GLOBAL source so LDS dest stays linear.
// 1D grid; XCD-contiguous remap + 4x4 supertiles for L2 locality (R3).
// Epilogue: acc -> LDS tile -> coalesced bf16x8 stores; EPI=4 stages fp32
// in two 128-row passes (single bf16 rounding of h = Z*inv + x, R5).
// EPI: 0 = +bias[n] + pos_enc[m%SEQ][n]                     (embed)
//      3 = exp(v/32), write P' + rowsum atomics             (scores)
//      4 = (Z/rowsum[m]) + resid[m][n] (fp32 staging)       (P'*V + x -> h)
//      5 = logits[m] += sum_n tanh(C)*sq[n], no C write     (soft_key)
//      6 = fused QKV: N=3072; seg=ntile>>10 -> Q | K | V^T  (+ per-seg bias)
// ---------------------------------------------------------------------------

#define PH_DS(AB_, BB_, QM, QN)                                               \
    _Pragma("unroll")                                                         \
    for (int s_ = 0; s_ < 2; ++s_) {                                          \
        const int po_ = (((s_ << 2) | lq) ^ lr7) << 3;                        \
        _Pragma("unroll")                                                     \
        for (int t_ = 0; t_ < 4; ++t_)                                        \
            af[s_][t_] = *(const bf16x8*)&(AB_)[(wrow + (QM)*64 + t_*16 + lr)*64 + po_]; \
        _Pragma("unroll")                                                     \
        for (int u_ = 0; u_ < 2; ++u_)                                        \
            bfv[s_][u_] = *(const bf16x8*)&(BB_)[(wcol + (QN)*32 + u_*16 + lr)*64 + po_]; \
    }

#define PH_MM(QM, QN)                                                         \
    __builtin_amdgcn_s_barrier();                                             \
    asm volatile("s_waitcnt lgkmcnt(0)");                                     \
    __builtin_amdgcn_s_setprio(1);                                            \
    _Pragma("unroll")                                                         \
    for (int s_ = 0; s_ < 2; ++s_) {                                          \
        _Pragma("unroll")                                                     \
        for (int t_ = 0; t_ < 4; ++t_) {                                      \
            _Pragma("unroll")                                                 \
            for (int u_ = 0; u_ < 2; ++u_)                                    \
                acc[(QM)*4 + t_][(QN)*2 + u_] =                               \
                    __builtin_amdgcn_mfma_f32_16x16x32_bf16(af[s_][t_], bfv[s_][u_], \
                        acc[(QM)*4 + t_][(QN)*2 + u_], 0, 0, 0);              \
        }                                                                     \
    }                                                                         \
    __builtin_amdgcn_s_setprio(0);

#define PH_END                                                                \
    __builtin_amdgcn_s_barrier();                                             \
    asm volatile("" ::: "memory");

// region stage: Q=0 -> A rows [0,64)u[128,192) / B rows [0,32)u[64,96)u...
//               Q=1 -> complements. 2 x global_load_lds (16B) per wave.
#define STAGE_A(Q, DST, KO) {                                                 \
    _Pragma("unroll")                                                         \
    for (int j_ = 0; j_ < 2; ++j_) {                                          \
        const int i_ = (wid << 1) | j_;                                       \
        const int g_ = i_ + (i_ & 8) + ((Q) << 3);                            \
        async16(Ag + (long)((g_ << 3) + srow8) * K + (KO) + sk, (DST) + (g_ << 9)); \
    } }

#define STAGE_B(Q, DST, KO) {                                                 \
    _Pragma("unroll")                                                         \
    for (int j_ = 0; j_ < 2; ++j_) {                                          \
        const int i_ = (wid << 1) | j_;                                       \
        const int g_ = (((i_ & 12) << 1) | (i_ & 3)) + ((Q) << 2);            \
        async16(Bg + (long)((g_ << 3) + srow8) * K + (KO) + sk, (DST) + (g_ << 9)); \
    } }

template<int EPI>
__global__ __launch_bounds__(512, 2)
void gemm_bt(const bf16_t* __restrict__ Ab, const bf16_t* __restrict__ Bb,
             bf16_t* __restrict__ Cb, int K, int ldc, int gx, int gy,
             long batchA, long batchB, long batchC,
             const float* __restrict__ bias, const float* __restrict__ aux_f,
             const bf16_t* __restrict__ resid, float* __restrict__ logits,
             const float* __restrict__ bias3)
{
    __shared__ __align__(16) bf16_t smem[65536];   // 128 KB: 2x(As|Bs); epilogue C tile

    const int tid  = threadIdx.x;
    const int lane = tid & 63;
    const int wid  = tid >> 6;          // 0..7
    const int wr   = wid >> 2;          // 0..1  (2 waves in M)
    const int wc   = wid & 3;           // 0..3  (4 waves in N)

    // --- block swizzle: XCD-contiguous + 4x4 supertiles ---
    const int flat = blockIdx.x;
    const int nb   = gridDim.x;                    // multiple of 8
    const int vid  = (flat & 7) * (nb >> 3) + (flat >> 3);
    const int pb   = gx * gy;                      // blocks per batch
    const int z    = vid / pb;
    const int w    = vid - z * pb;
    const int sy   = w / (gx * 4);
    const int r    = w - sy * (gx * 4);
    const int sx   = r >> 4;
    const int inner= r & 15;
    const int mtile = (sy * 4 + (inner & 3)) * 256;
    const int ntile = (sx * 4 + (inner >> 2)) * 256;

    const bf16_t* Ag = Ab + (long)z * batchA + (long)mtile * K;
    const bf16_t* Bg = Bb + (long)z * batchB + (long)ntile * K;

    f32x4 acc[8][4];
    #pragma unroll
    for (int i = 0; i < 8; ++i)
        #pragma unroll
        for (int j = 0; j < 4; ++j)
            acc[i][j] = (f32x4)(0.f);

    const int lr  = lane & 15;         // fragment row-in-tile
    const int lr7 = lr & 7;
    const int lq  = lane >> 4;         // quad 0..3
    const int wrow = wr * 128;
    const int wcol = wc * 64;

    // staging: one async16 covers 8 rows (8 lanes/row, 16 B each)
    const int srow8 = lane >> 3;                       // 0..7
    const int sk    = ((lane & 7) ^ srow8) * 8;        // swizzled logical k-off

    bf16_t* const A0 = smem;            // buf0: even K-tiles
    bf16_t* const B0 = smem + 16384;
    bf16_t* const A1 = smem + 32768;    // buf1: odd K-tiles
    bf16_t* const B1 = smem + 49152;

    const int niter = K >> 7;           // 2 K-tiles (of 64) per iteration

    // prologue: tile 0 -> buf0, tile 1 -> buf1 (16 loads/wave)
    STAGE_A(0, A0, 0);  STAGE_A(1, A0, 0);
    STAGE_B(0, B0, 0);  STAGE_B(1, B0, 0);
    STAGE_A(0, A1, 64); STAGE_A(1, A1, 64);
    STAGE_B(0, B1, 64); STAGE_B(1, B1, 64);
    asm volatile("s_waitcnt vmcnt(8)" ::: "memory");   // tile 0 landed
    __builtin_amdgcn_s_barrier();
    asm volatile("" ::: "memory");

    for (int it = 0; it < niter; ++it) {
        const int kb = it << 7;
        const bool nf   = (it > 0);
        const bool more = (it + 1 < niter);
        bf16x8 af[2][4], bfv[2][2];

        // ---- tile 2it (buf0) ----
        PH_DS(A0, B0, 0, 0);
        if (nf) { STAGE_A(1, A1, kb + 64); }      // (2it+1).Aq1
        PH_MM(0, 0); PH_END;

        PH_DS(A0, B0, 0, 1);
        if (nf) { STAGE_B(1, B1, kb + 64); }      // (2it+1).Bq1
        PH_MM(0, 1); PH_END;

        PH_DS(A0, B0, 1, 0);
        if (more) { STAGE_A(0, A0, kb + 128); }   // (2it+2).Aq0
        PH_MM(1, 0); PH_END;

        PH_DS(A0, B0, 1, 1);
        if (more) { STAGE_B(0, B0, kb + 128); }   // (2it+2).Bq0
        PH_MM(1, 1);
        if (more) asm volatile("s_waitcnt vmcnt(4)" ::: "memory"); // tile 2it+1 ready
        else      asm volatile("s_waitcnt vmcnt(0)" ::: "memory");
        PH_END;

        // ---- tile 2it+1 (buf1) ----
        PH_DS(A1, B1, 0, 0);
        if (more) { STAGE_A(1, A0, kb + 128); }   // (2it+2).Aq1
        PH_MM(0, 0); PH_END;

        PH_DS(A1, B1, 0, 1);
        if (more) { STAGE_B(1, B0, kb + 128); }   // (2it+2).Bq1
        PH_MM(0, 1); PH_END;

        PH_DS(A1, B1, 1, 0);
        if (more) { STAGE_A(0, A1, kb + 192); }   // (2it+3).Aq0
        PH_MM(1, 0); PH_END;

        PH_DS(A1, B1, 1, 1);
        if (more) { STAGE_B(0, B1, kb + 192); }   // (2it+3).Bq0
        PH_MM(1, 1);
        if (more) asm volatile("s_waitcnt vmcnt(4)" ::: "memory"); // tile 2it+2 ready
        else      asm volatile("s_waitcnt vmcnt(0)" ::: "memory");
        PH_END;
    }

    // C/D layout: n = lane&15, m = (lane>>4)*4 + reg  [m89-verified]
    if constexpr (EPI == 5) {
        const int mb = mtile + wrow + lq * 4;
        #pragma unroll
        for (int fm = 0; fm < 8; ++fm) {
            #pragma unroll
            for (int reg = 0; reg < 4; ++reg) {
                const int m = mb + fm * 16 + reg;
                float rs = 0.f;
                #pragma unroll
                for (int fn = 0; fn < 4; ++fn) {
                    const int n = ntile + wcol + fn * 16 + lr;
                    rs += tanhf(acc[fm][fn][reg]) * aux_f[n];
                }
                rs += __shfl_xor(rs, 1);
                rs += __shfl_xor(rs, 2);
                rs += __shfl_xor(rs, 4);
                rs += __shfl_xor(rs, 8);
                if (lr == 0) atomicAdd(&logits[m], rs);
            }
        }
        return;
    }

    __syncthreads();                   // all waves done with K-loop LDS

    if constexpr (EPI == 4) {
        // fp32 LDS staging in two 128-row passes: single bf16 rounding of
        // h = Z*inv + x.  fsm = [128][256] fp32 (exactly 128 KB).
        float* fsm = (float*)smem;
        bf16_t* C = Cb + (long)z * batchC;
        const float* rsum = bias + (long)z * SEQ;      // rowsum passed via bias
        #pragma unroll
        for (int half = 0; half < 2; ++half) {
            if (half) __syncthreads();
            if (wr == half) {
                #pragma unroll
                for (int fm = 0; fm < 8; ++fm) {
                    #pragma unroll
                    for (int reg = 0; reg < 4; ++reg) {
                        const int rl = fm * 16 + lq * 4 + reg;      // 0..127
                        #pragma unroll
                        for (int fn = 0; fn < 4; ++fn) {
                            const int cl = wcol + fn * 16 + lr;     // 0..255
                            const int ph = (cl >> 2) ^ (rl & 31);   // bit5 kept
                            fsm[rl * 256 + (ph << 2) + (cl & 3)] = acc[fm][fn][reg];
                        }
                    }
                }
            }
            __syncthreads();
            const int chunk = tid & 31;    // 8 consecutive cols
            const int grp   = tid >> 5;
            #pragma unroll
            for (int rep = 0; rep < 8; ++rep) {
                const int R  = grp + (rep << 4);                    // 0..127
                const int c0 = chunk << 3;
                const int p0 = (c0 >> 2) ^ (R & 31);
                const f32x4 f0 = *(const f32x4*)&fsm[R * 256 + (p0 << 2)];
                const f32x4 f1 = *(const f32x4*)&fsm[R * 256 + ((p0 ^ 1) << 2)];
                const int Rg = half * 128 + R;
                const float inv = 1.f / rsum[mtile + Rg];
                const long off = (long)(mtile + Rg) * ldc + ntile + c0;
                const bf16x8 r8 = *(const bf16x8*)&resid[(long)z * batchC + off];
                bf16x8 val;
                #pragma unroll
                for (int i = 0; i < 4; ++i) {
                    val[i]     = (bf16_t)(f0[i] * inv + (float)r8[i]);
                    val[i + 4] = (bf16_t)(f1[i] * inv + (float)r8[i + 4]);
                }
                *(bf16x8*)&C[off] = val;
            }
        }
        return;
    }

    const int seg = (EPI == 6) ? (ntile >> 10) : 0;
    const float* bp = bias;
    if constexpr (EPI == 6) bp = (seg == 0) ? bias : (seg == 1) ? aux_f : bias3;

    // stage 1: registers -> LDS bf16 (col-chunk XOR row&7 swizzle)
    #pragma unroll
    for (int fm = 0; fm < 8; ++fm) {
        #pragma unroll
        for (int reg = 0; reg < 4; ++reg) {
            const int rl = wrow + fm * 16 + lq * 4 + reg;        // 0..255
            #pragma unroll
            for (int fn = 0; fn < 4; ++fn) {
                const int cl = wcol + fn * 16 + lr;              // 0..255
                float v = acc[fm][fn][reg];
                if constexpr (EPI == 0)
                    v += bias[ntile + cl] + aux_f[((mtile + rl) & (SEQ-1))*DMODEL + ntile + cl];
                if constexpr (EPI == 3) v = __expf(v * 0.03125f);  // exp(s/sqrt(D))
                if constexpr (EPI == 6) v += bp[(ntile + cl) & 1023];
                smem[rl * 256 + ((((cl >> 3) ^ (rl & 7)) << 3) | (cl & 7))] = (bf16_t)v;
            }
        }
    }
    __syncthreads();

    // stage 2: LDS -> global, coalesced
    if constexpr (EPI == 3) {
        bf16_t* C = Cb + (long)z * batchC;
        float* rsum = logits + (long)z * SEQ;          // rowsum passed via logits
        const int chunk = tid & 31;
        const int grp   = tid >> 5;
        #pragma unroll
        for (int rep = 0; rep < 16; ++rep) {
            const int R = grp + (rep << 4);
            const int phys = chunk ^ (R & 7);
            bf16x8 val = *(const bf16x8*)&smem[R * 256 + (phys << 3)];
            const long off = (long)(mtile + R) * ldc + ntile + (chunk << 3);
            *(bf16x8*)&C[off] = val;
            float ps = 0.f;
            #pragma unroll
            for (int i = 0; i < 8; ++i) ps += (float)val[i];
            ps += __shfl_xor(ps, 1);
            ps += __shfl_xor(ps, 2);
            ps += __shfl_xor(ps, 4);
            ps += __shfl_xor(ps, 8);
            ps += __shfl_xor(ps, 16);
            if (chunk == 0) atomicAdd(&rsum[mtile + R], ps);
        }
        return;
    }

    if constexpr (EPI == 6) {
        if (seg == 2) {
            // V transposed: VT[b][n][s]; contiguous dim = s = m
            bf16_t* VTb = Cb + 33554432;                     // Qb + 32M elems
            const int col  = tid & 255;                      // n_local within tile
            const int half = tid >> 8;
            const int b    = mtile >> 11, s0 = mtile & (SEQ-1);
            const long nbase = (long)b*DMODEL + (ntile & 1023) + col;
            #pragma unroll
            for (int rep = 0; rep < 16; ++rep) {
                const int R0 = half * 128 + rep * 8;
                bf16x8 o;
                #pragma unroll
                for (int i = 0; i < 8; ++i) {
                    const int rl = R0 + i;
                    o[i] = smem[rl * 256 + ((((col >> 3) ^ (rl & 7)) << 3) | (col & 7))];
                }
                *(bf16x8*)&VTb[nbase * SEQ + s0 + R0] = o;
            }
            return;
        }
        const int chunk = tid & 31;
        const int grp   = tid >> 5;
        const long base = (long)seg * 16777216 + (ntile & 1023) + (chunk << 3);
        #pragma unroll
        for (int rep = 0; rep < 16; ++rep) {
            const int R = grp + (rep << 4);
            const int phys = chunk ^ (R & 7);
            bf16x8 val = *(const bf16x8*)&smem[R * 256 + (phys << 3)];
            *(bf16x8*)&Cb[base + (long)(mtile + R) * 1024] = val;
        }
        return;
    }

    bf16_t* C = Cb + (long)z * batchC;
    const int chunk = tid & 31;
    const int grp   = tid >> 5;
    #pragma unroll
    for (int rep = 0; rep < 16; ++rep) {
        const int R = grp + (rep << 4);
        const int phys = chunk ^ (R & 7);
        bf16x8 val = *(const bf16x8*)&smem[R * 256 + (phys << 3)];
        const long off = (long)(mtile + R) * ldc + ntile + (chunk << 3);
        *(bf16x8*)&C[off] = val;
    }
}

// ---------------------------------------------------------------------------
// All fp32->bf16 casts + logits/rowsum zeroing in ONE launch.
__global__ __launch_bounds__(256) void cast_all(
        const float* __restrict__ inp, const float* __restrict__ emw,
        const float* __restrict__ wqw, const float* __restrict__ wkw,
        const float* __restrict__ wvw, const float* __restrict__ skw,
        bf16_t* __restrict__ in_b, bf16_t* __restrict__ we_b,
        bf16_t* __restrict__ wq_b, bf16_t* __restrict__ wk_b,
        bf16_t* __restrict__ wv_b, bf16_t* __restrict__ sk_b,
        float* __restrict__ logits, float* __restrict__ rowsum) {
    const int i = blockIdx.x*256 + threadIdx.x;
    const float* s; bf16_t* d; int j;
    if      (i < 2097152) { s = inp; d = in_b; j = i; }
    else if (i < 2228224) { s = emw; d = we_b; j = i - 2097152; }
    else if (i < 2490368) { s = wqw; d = wq_b; j = i - 2228224; }
    else if (i < 2752512) { s = wkw; d = wk_b; j = i - 2490368; }
    else if (i < 3014656) { s = wvw; d = wv_b; j = i - 2752512; }
    else if (i < 3276800) { s = skw; d = sk_b; j = i - 3014656; }
    else if (i < 3280896) { ((f32x4*)logits)[i - 3276800] = (f32x4)(0.f); return; }
    else                  { ((f32x4*)rowsum)[i - 3280896] = (f32x4)(0.f); return; }
    const float4 f = ((const float4*)s)[j];
    bf16x4 o;
    o[0] = (bf16_t)f.x; o[1] = (bf16_t)f.y; o[2] = (bf16_t)f.z; o[3] = (bf16_t)f.w;
    ((bf16x4*)d)[j] = o;
}

// LayerNorm over 1024: one block per row, h bf16 -> H bf16 (vectorized)
__global__ __launch_bounds__(256) void layernorm_k(const bf16_t* __restrict__ h, bf16_t* __restrict__ H,
                                                   const float* __restrict__ gam, const float* __restrict__ bet) {
    const long row = blockIdx.x;
    const bf16_t* hr = h + row*DMODEL;
    bf16_t* Hr = H + row*DMODEL;
    const int t = threadIdx.x, lane = t & 63, wave = t >> 6;
    __shared__ float sm[8];
    const bf16x4 hv = *(const bf16x4*)&hr[t*4];
    float v[4]; float s = 0.f, q = 0.f;
    #pragma unroll
    for (int j = 0; j < 4; ++j) { v[j] = (float)hv[j]; s += v[j]; q += v[j]*v[j]; }
    #pragma unroll
    for (int o = 32; o; o >>= 1) { s += __shfl_xor(s, o); q += __shfl_xor(q, o); }
    if (lane == 0) { sm[wave] = s; sm[4 + wave] = q; }
    __syncthreads();
    s = (sm[0] + sm[1]) + (sm[2] + sm[3]);
    q = (sm[4] + sm[5]) + (sm[6] + sm[7]);
    const float mu  = s * (1.f/DMODEL);
    const float var = q * (1.f/DMODEL) - mu*mu;
    const float r   = rsqrtf(var + 1e-5f);
    const float4 g4 = ((const float4*)gam)[t];
    const float4 b4 = ((const float4*)bet)[t];
    bf16x4 o4;
    o4[0] = (bf16_t)((v[0] - mu)*r*g4.x + b4.x);
    o4[1] = (bf16_t)((v[1] - mu)*r*g4.y + b4.y);
    o4[2] = (bf16_t)((v[2] - mu)*r*g4.z + b4.z);
    o4[3] = (bf16_t)((v[3] - mu)*r*g4.w + b4.w);
    *(bf16x4*)&Hr[t*4] = o4;
}

// ---------------------------------------------------------------------------
// Pooling stage 1 with fused per-batch logit softmax.
__global__ __launch_bounds__(256) void pool_partial(const float* __restrict__ logits,
                                                    const bf16_t* __restrict__ H,
                                                    float* __restrict__ part) {
    const int b = blockIdx.y;
    const int c = blockIdx.x;
    const int t = threadIdx.x, lane = t & 63, wave = t >> 6;
    __shared__ float sm[8];
    __shared__ float wsm[32];
    const float* lb = logits + b*SEQ;
    const float4 a4 = ((const float4*)lb)[t];
    const float4 c4 = ((const float4*)lb)[t + 256];
    float v[8] = {a4.x, a4.y, a4.z, a4.w, c4.x, c4.y, c4.z, c4.w};
    float mx = -3.0e38f;
    #pragma unroll
    for (int j = 0; j < 8; ++j) mx = fmaxf(mx, v[j]);
    #pragma unroll
    for (int o = 32; o; o >>= 1) mx = fmaxf(mx, __shfl_xor(mx, o));
    if (lane == 0) sm[wave] = mx;
    __syncthreads();
    mx = fmaxf(fmaxf(sm[0], sm[1]), fmaxf(sm[2], sm[3]));
    float s = 0.f;
    #pragma unroll
    for (int j = 0; j < 8; ++j) s += __expf(v[j] - mx);
    #pragma unroll
    for (int o = 32; o; o >>= 1) s += __shfl_xor(s, o);
    if (lane == 0) sm[4 + wave] = s;
    __syncthreads();
    s = (sm[4] + sm[5]) + (sm[6] + sm[7]);
    const float inv = 1.f / s;
    if (t < 32) wsm[t] = __expf(lb[c*32 + t] - mx) * inv;
    __syncthreads();

    const bf16_t* Hb = H + ((long)b*SEQ + (long)c*32)*DMODEL;
    f32x4 acc = (f32x4)(0.f);
    #pragma unroll 4
    for (int i = 0; i < 32; ++i) {
        const float wi = wsm[i];
        const bf16x4 hv = *(const bf16x4*)&Hb[(long)i*DMODEL + t*4];
        acc[0] += wi * (float)hv[0];
        acc[1] += wi * (float)hv[1];
        acc[2] += wi * (float)hv[2];
        acc[3] += wi * (float)hv[3];
    }
    *(f32x4*)&part[((long)b*64 + c)*DMODEL + t*4] = acc;
}

// stage 2: out[b][o] = sum_c part[b][c][o]; 8192 threads
__global__ __launch_bounds__(256) void pool_reduce(const float* __restrict__ part,
                                                   float* __restrict__ out) {
    const int i = blockIdx.x*256 + threadIdx.x;   // 0..8191
    const int b = i >> 10, o = i & 1023;
    const float* p = part + (long)b*64*DMODEL + o;
    float s = 0.f;
    #pragma unroll
    for (int c = 0; c < 64; ++c) s += p[c*DMODEL];
    out[i] = s;
}

// ---------------------------------------------------------------------------
extern "C" void kernel_launch(void* const* d_in, const int* in_sizes, int n_in,
                              void* d_out, int out_size, void* d_ws, size_t ws_size,
                              hipStream_t stream) {
    (void)in_sizes; (void)n_in; (void)out_size; (void)ws_size;
    const float* inp = (const float*)d_in[0];
    const float* emw = (const float*)d_in[1];
    const float* emb = (const float*)d_in[2];
    const float* wqw = (const float*)d_in[3];
    const float* wqb = (const float*)d_in[4];
    const float* wkw = (const float*)d_in[5];
    const float* wkb = (const float*)d_in[6];
    const float* wvw = (const float*)d_in[7];
    const float* wvb = (const float*)d_in[8];
    const float* lng = (const float*)d_in[9];
    const float* lnb = (const float*)d_in[10];
    const float* skw = (const float*)d_in[11];
    const float* sq  = (const float*)d_in[12];
    const float* pos = (const float*)d_in[13];
    float* out = (float*)d_out;

    char* ws = (char*)d_ws;
    bf16_t* in_b   = (bf16_t*)(ws + 0);            // 16 MB (dead after embed; reused by pool partials)
    bf16_t* we_b   = (bf16_t*)(ws + 16777216);     // 1 MB
    bf16_t* wq_b   = (bf16_t*)(ws + 17825792);     // 2 MB  } contiguous [3072][1024]
    bf16_t* wk_b   = (bf16_t*)(ws + 19922944);     // 2 MB  }
    bf16_t* wv_b   = (bf16_t*)(ws + 22020096);     // 2 MB  }
    bf16_t* sk_b   = (bf16_t*)(ws + 24117248);     // 2 MB
    float*  logits = (float*)(ws + 26214400);      // 64 KB
    float*  rowsum = (float*)(ws + 26279936);      // 64 KB (softmax denominators)
    bf16_t* xb     = (bf16_t*)(ws + 26345472);     // 32 MB  x (bf16)
    bf16_t* Qb     = (bf16_t*)(ws + 59899904);     // 32 MB  Q, later h   } Q|K|VT contiguous
    bf16_t* Kb     = (bf16_t*)(ws + 93454336);     // 32 MB               }
    bf16_t* VT     = (bf16_t*)(ws + 127008768);    // 32 MB  V^T [b][1024][2048]
    bf16_t* Hb     = (bf16_t*)(ws + 160563200);    // 32 MB
    bf16_t* Pb     = (bf16_t*)(ws + 194117632);    // 64 MB  P' = exp(scores)
    float*  part   = (float*)(ws + 0);             // 2 MB pool partials (aliases dead in_b)

    // all casts + logits/rowsum zero, one launch
    cast_all<<<12832, 256, 0, stream>>>(inp, emw, wqw, wkw, wvw, skw,
                                        in_b, we_b, wq_b, wk_b, wv_b, sk_b,
                                        logits, rowsum);

    // x = inputs @ embed_w^T + bias + pos       (gx=4 n-tiles, gy=64 m-tiles)
    gemm_bt<0><<<256, 512, 0, stream>>>(in_b, we_b, xb, D_IN, DMODEL, 4, 64,
        0, 0, 0, emb, pos, nullptr, nullptr, nullptr);
    // fused QKV: N=3072 over contiguous weights; writes Q | K | VT
    gemm_bt<6><<<768, 512, 0, stream>>>(xb, wq_b, Qb, DMODEL, DMODEL, 12, 64,
        0, 0, 0, wqb, wkb, nullptr, nullptr, wvb);
    // P' = exp(Q K^T / 32) per batch + rowsum atomics   (one batch per XCD)
    gemm_bt<3><<<512, 512, 0, stream>>>(Qb, Kb, Pb, DMODEL, SEQ, 8, 8,
        (long)SEQ*DMODEL, (long)SEQ*DMODEL, (long)SEQ*SEQ, nullptr, nullptr, nullptr, rowsum, nullptr);
    // h = (P' V)/rowsum + x  (written over Q buffer)
    gemm_bt<4><<<256, 512, 0, stream>>>(Pb, VT, Qb, SEQ, DMODEL, 4, 8,
        (long)SEQ*SEQ, (long)DMODEL*SEQ, (long)SEQ*DMODEL, rowsum, nullptr, xb, nullptr, nullptr);
    layernorm_k<<<NTOK, 256, 0, stream>>>(Qb, Hb, lng, lnb);
    // logits[m] = sum_n tanh(H skw^T) * soft_query[n]
    gemm_bt<5><<<256, 512, 0, stream>>>(Hb, sk_b, nullptr, DMODEL, 0, 4, 64,
        0, 0, 0, nullptr, sq, nullptr, logits, nullptr);
    // pooled output: fused softmax + two-stage parallel reduction
    pool_partial<<<dim3(64, BATCH), 256, 0, stream>>>(logits, Hb, part);
    pool_reduce<<<32, 256, 0, stream>>>(part, out);
}

// Round 2
// 479.673 us; speedup vs baseline: 1.0474x; 1.0474x over previous
//
#include <hip/hip_runtime.h>
#include <hip/hip_bf16.h>
#include <math.h>

typedef __bf16 bf16_t;
typedef bf16_t bf16x8 __attribute__((ext_vector_type(8)));
typedef bf16_t bf16x4 __attribute__((ext_vector_type(4)));
typedef float  f32x4  __attribute__((ext_vector_type(4)));

#define D_IN   512
#define DMODEL 1024
#define SEQ    2048
#define BATCH  8
#define NTOK   (BATCH*SEQ)

typedef __attribute__((address_space(1))) unsigned int gu32;
typedef __attribute__((address_space(3))) unsigned int lu32;

__device__ __forceinline__ void async16(const void* g, void* l) {
    __builtin_amdgcn_global_load_lds((gu32*)g, (lu32*)l, 16, 0, 0);
}

// ---------------------------------------------------------------------------
// Unified bf16 GEMM: C[M,N] = A[M,K] * B[N,K]^T  (both row-major over K)
// R14: 256x256 tile, 8-wave (512 thr), BK=64, 2 K-tiles/iter, 8-phase.
// R13 post-mortem: quadrant-major phases read every fragment TWICE
// (48 ds_read_b128/K-tile vs 24 minimum) -> LDS-read-BW bound (741 TF =
// exactly half of m201's 1563).  R14 phases are (k-substep x m-half):
//   p1: ld B(s0)x4 + A(s0,mh0)x4 -> 16 MFMA    p2: B(s1)+A(s1,mh0) -> 16
//   p3: A(s0,mh1)x4 (B s0 in regs) -> 16        p4: A(s1,mh1) -> 16
// = 24 reads/K-tile, each fragment read once ("4 or 8 per phase", m201).
// Staging (2 global_load_lds x16B per wave per region):
//   p1: T+1.Aq1 | p3: T+2.Aq0+Bq0 | p4: T+2.Bq1 | p5: T+2.Aq1
//   p7: T+3.Aq0+Bq0 | p8: T+3.Bq1    (T = tile 2it, buf = tile&1)
// Region deaths under the new read pattern: B,Aq0 die p2/p6; Aq1 p4/p8 --
// every stage lands after the barrier following its region's last read.
// vmcnt: uniform vmcnt(8) at p2/p4/p6/p8 ends (5-phase latency cover,
// verified vs per-wave outstanding queue incl. prologue & it=0); drain
// tail vmcnt(2)@p4, vmcnt(0)@p6 on the last iteration.  Never vmcnt(0)
// in steady state (T4).  setprio(1) around each 16-MFMA cluster (T5).
// Swizzle: 16B chunk phys = logical ^ (row&7); staging pre-swizzles the
// GLOBAL source so LDS dest stays linear. 0 bank conflicts since R3.
// 1D grid; XCD-contiguous remap + 4x4 supertiles for L2 locality (R3).
// EPI: 0 = +bias[n] + pos_enc[m%SEQ][n]                     (embed)
//      3 = exp(v/32), write P' + rowsum atomics             (scores)
//      4 = (Z/rowsum[m]) + resid[m][n] (fp32 staging)       (P'*V + x -> h)
//      5 = logits[m] += sum_n tanh(C)*sq[n], no C write     (soft_key)
//      6 = fused QKV: N=3072; seg=ntile>>10 -> Q | K | V^T  (+ per-seg bias)
// ---------------------------------------------------------------------------

#define LD_B(BUF, S) {                                                        \
    const int po_ = ((((S) << 2) | lq) ^ lr7) << 3;                           \
    _Pragma("unroll")                                                         \
    for (int u_ = 0; u_ < 4; ++u_)                                            \
        bfv[S][u_] = *(const bf16x8*)&(BUF)[(wcol + u_*16 + lr)*64 + po_];    \
    }

#define LD_A(BUF, S, MH) {                                                    \
    const int po_ = ((((S) << 2) | lq) ^ lr7) << 3;                           \
    _Pragma("unroll")                                                         \
    for (int t_ = 0; t_ < 4; ++t_)                                            \
        af[t_] = *(const bf16x8*)&(BUF)[(wrow + (MH)*64 + t_*16 + lr)*64 + po_]; \
    }

#define MM(S, MH)                                                             \
    __builtin_amdgcn_s_barrier();                                             \
    asm volatile("s_waitcnt lgkmcnt(0)");                                     \
    __builtin_amdgcn_s_setprio(1);                                            \
    _Pragma("unroll")                                                         \
    for (int t_ = 0; t_ < 4; ++t_) {                                          \
        _Pragma("unroll")                                                     \
        for (int u_ = 0; u_ < 4; ++u_)                                        \
            acc[(MH)*4 + t_][u_] = __builtin_amdgcn_mfma_f32_16x16x32_bf16(   \
                af[t_], bfv[S][u_], acc[(MH)*4 + t_][u_], 0, 0, 0);           \
    }                                                                         \
    __builtin_amdgcn_s_setprio(0);

#define PH_END                                                                \
    __builtin_amdgcn_s_barrier();                                             \
    asm volatile("" ::: "memory");

// region stage: Q=0 -> A rows [0,64)u[128,192) / B rows [0,32)u[64,96)u...
//               Q=1 -> complements. 2 x global_load_lds (16B) per wave.
#define STAGE_A(Q, DST, KO) {                                                 \
    _Pragma("unroll")                                                         \
    for (int j_ = 0; j_ < 2; ++j_) {                                          \
        const int i_ = (wid << 1) | j_;                                       \
        const int g_ = i_ + (i_ & 8) + ((Q) << 3);                            \
        async16(Ag + (long)((g_ << 3) + srow8) * K + (KO) + sk, (DST) + (g_ << 9)); \
    } }

#define STAGE_B(Q, DST, KO) {                                                 \
    _Pragma("unroll")                                                         \
    for (int j_ = 0; j_ < 2; ++j_) {                                          \
        const int i_ = (wid << 1) | j_;                                       \
        const int g_ = (((i_ & 12) << 1) | (i_ & 3)) + ((Q) << 2);            \
        async16(Bg + (long)((g_ << 3) + srow8) * K + (KO) + sk, (DST) + (g_ << 9)); \
    } }

template<int EPI>
__global__ __launch_bounds__(512, 2)
void gemm_bt(const bf16_t* __restrict__ Ab, const bf16_t* __restrict__ Bb,
             bf16_t* __restrict__ Cb, int K, int ldc, int gx, int gy,
             long batchA, long batchB, long batchC,
             const float* __restrict__ bias, const float* __restrict__ aux_f,
             const bf16_t* __restrict__ resid, float* __restrict__ logits,
             const float* __restrict__ bias3)
{
    __shared__ __align__(16) bf16_t smem[65536];   // 128 KB: 2x(As|Bs); epilogue C tile

    const int tid  = threadIdx.x;
    const int lane = tid & 63;
    const int wid  = tid >> 6;          // 0..7
    const int wr   = wid >> 2;          // 0..1  (2 waves in M)
    const int wc   = wid & 3;           // 0..3  (4 waves in N)

    // --- block swizzle: XCD-contiguous + 4x4 supertiles ---
    const int flat = blockIdx.x;
    const int nb   = gridDim.x;                    // multiple of 8
    const int vid  = (flat & 7) * (nb >> 3) + (flat >> 3);
    const int pb   = gx * gy;                      // blocks per batch
    const int z    = vid / pb;
    const int w    = vid - z * pb;
    const int sy   = w / (gx * 4);
    const int r    = w - sy * (gx * 4);
    const int sx   = r >> 4;
    const int inner= r & 15;
    const int mtile = (sy * 4 + (inner & 3)) * 256;
    const int ntile = (sx * 4 + (inner >> 2)) * 256;

    const bf16_t* Ag = Ab + (long)z * batchA + (long)mtile * K;
    const bf16_t* Bg = Bb + (long)z * batchB + (long)ntile * K;

    f32x4 acc[8][4];
    #pragma unroll
    for (int i = 0; i < 8; ++i)
        #pragma unroll
        for (int j = 0; j < 4; ++j)
            acc[i][j] = (f32x4)(0.f);

    const int lr  = lane & 15;         // fragment row-in-tile
    const int lr7 = lr & 7;
    const int lq  = lane >> 4;         // quad 0..3
    const int wrow = wr * 128;
    const int wcol = wc * 64;

    // staging: one async16 covers 8 rows (8 lanes/row, 16 B each)
    const int srow8 = lane >> 3;                       // 0..7
    const int sk    = ((lane & 7) ^ srow8) * 8;        // swizzled logical k-off

    bf16_t* const A0 = smem;            // buf0: even K-tiles
    bf16_t* const B0 = smem + 16384;
    bf16_t* const A1 = smem + 32768;    // buf1: odd K-tiles
    bf16_t* const B1 = smem + 49152;

    const int niter = K >> 7;           // 2 K-tiles (of 64) per iteration

    // prologue: tile0 full (Aq0+Bq0, Bq1, Aq1) + tile1 partial (Aq0+Bq0, Bq1);
    // tile1.Aq1 staged at it0.p1 (steady-state slot).
    STAGE_A(0, A0, 0);  STAGE_B(0, B0, 0);
    STAGE_B(1, B0, 0);  STAGE_A(1, A0, 0);
    STAGE_A(0, A1, 64); STAGE_B(0, B1, 64);
    STAGE_B(1, B1, 64);
    asm volatile("s_waitcnt vmcnt(8)" ::: "memory");   // tile0 Aq0,Bq0,Bq1 landed
    __builtin_amdgcn_s_barrier();
    asm volatile("" ::: "memory");

    for (int it = 0; it < niter; ++it) {
        const int kb = it << 7;
        const bool more = (it + 1 < niter);
        bf16x8 af[4], bfv[2][4];

        // ---- tile 2it (buf0) ----
        // p1: s0, mh0 ; stage (2it+1).Aq1
        LD_B(B0, 0); LD_A(A0, 0, 0);
        STAGE_A(1, A1, kb + 64);
        MM(0, 0);
        PH_END;

        // p2: s1, mh0
        LD_B(B0, 1); LD_A(A0, 1, 0);
        MM(1, 0);
        asm volatile("s_waitcnt vmcnt(8)" ::: "memory");   // (2it).Aq1 confirmed
        PH_END;

        // p3: s0, mh1 ; stage (2it+2).Aq0+Bq0
        LD_A(A0, 0, 1);
        if (more) { STAGE_A(0, A0, kb + 128); STAGE_B(0, B0, kb + 128); }
        MM(0, 1);
        PH_END;

        // p4: s1, mh1 ; stage (2it+2).Bq1
        LD_A(A0, 1, 1);
        if (more) { STAGE_B(1, B0, kb + 128); }
        MM(1, 1);
        if (more) asm volatile("s_waitcnt vmcnt(8)" ::: "memory"); // (2it+1).Aq0,B ready
        else      asm volatile("s_waitcnt vmcnt(2)" ::: "memory");
        PH_END;

        // ---- tile 2it+1 (buf1) ----
        // p5: s0, mh0 ; stage (2it+2).Aq1
        LD_B(B1, 0); LD_A(A1, 0, 0);
        if (more) { STAGE_A(1, A0, kb + 128); }
        MM(0, 0);
        PH_END;

        // p6: s1, mh0
        LD_B(B1, 1); LD_A(A1, 1, 0);
        MM(1, 0);
        if (more) asm volatile("s_waitcnt vmcnt(8)" ::: "memory"); // (2it+1).Aq1 confirmed
        else      asm volatile("s_waitcnt vmcnt(0)" ::: "memory");
        PH_END;

        // p7: s0, mh1 ; stage (2it+3).Aq0+Bq0
        LD_A(A1, 0, 1);
        if (more) { STAGE_A(0, A1, kb + 192); STAGE_B(0, B1, kb + 192); }
        MM(0, 1);
        PH_END;

        // p8: s1, mh1 ; stage (2it+3).Bq1
        LD_A(A1, 1, 1);
        if (more) { STAGE_B(1, B1, kb + 192); }
        MM(1, 1);
        if (more) asm volatile("s_waitcnt vmcnt(8)" ::: "memory"); // (2it+2).Aq0,B ready
        PH_END;
    }

    // C/D layout: n = lane&15, m = (lane>>4)*4 + reg  [m89-verified]
    if constexpr (EPI == 5) {
        const int mb = mtile + wrow + lq * 4;
        #pragma unroll
        for (int fm = 0; fm < 8; ++fm) {
            #pragma unroll
            for (int reg = 0; reg < 4; ++reg) {
                const int m = mb + fm * 16 + reg;
                float rs = 0.f;
                #pragma unroll
                for (int fn = 0; fn < 4; ++fn) {
                    const int n = ntile + wcol + fn * 16 + lr;
                    rs += tanhf(acc[fm][fn][reg]) * aux_f[n];
                }
                rs += __shfl_xor(rs, 1);
                rs += __shfl_xor(rs, 2);
                rs += __shfl_xor(rs, 4);
                rs += __shfl_xor(rs, 8);
                if (lr == 0) atomicAdd(&logits[m], rs);
            }
        }
        return;
    }

    __syncthreads();                   // all waves done with K-loop LDS

    if constexpr (EPI == 4) {
        // fp32 LDS staging in two 128-row passes: single bf16 rounding of
        // h = Z*inv + x.  fsm = [128][256] fp32 (exactly 128 KB).
        float* fsm = (float*)smem;
        bf16_t* C = Cb + (long)z * batchC;
        const float* rsum = bias + (long)z * SEQ;      // rowsum passed via bias
        #pragma unroll
        for (int half = 0; half < 2; ++half) {
            if (half) __syncthreads();
            if (wr == half) {
                #pragma unroll
                for (int fm = 0; fm < 8; ++fm) {
                    #pragma unroll
                    for (int reg = 0; reg < 4; ++reg) {
                        const int rl = fm * 16 + lq * 4 + reg;      // 0..127
                        #pragma unroll
                        for (int fn = 0; fn < 4; ++fn) {
                            const int cl = wcol + fn * 16 + lr;     // 0..255
                            const int ph = (cl >> 2) ^ (rl & 31);   // bit5 kept
                            fsm[rl * 256 + (ph << 2) + (cl & 3)] = acc[fm][fn][reg];
                        }
                    }
                }
            }
            __syncthreads();
            const int chunk = tid & 31;    // 8 consecutive cols
            const int grp   = tid >> 5;
            #pragma unroll
            for (int rep = 0; rep < 8; ++rep) {
                const int R  = grp + (rep << 4);                    // 0..127
                const int c0 = chunk << 3;
                const int p0 = (c0 >> 2) ^ (R & 31);
                const f32x4 f0 = *(const f32x4*)&fsm[R * 256 + (p0 << 2)];
                const f32x4 f1 = *(const f32x4*)&fsm[R * 256 + ((p0 ^ 1) << 2)];
                const int Rg = half * 128 + R;
                const float inv = 1.f / rsum[mtile + Rg];
                const long off = (long)(mtile + Rg) * ldc + ntile + c0;
                const bf16x8 r8 = *(const bf16x8*)&resid[(long)z * batchC + off];
                bf16x8 val;
                #pragma unroll
                for (int i = 0; i < 4; ++i) {
                    val[i]     = (bf16_t)(f0[i] * inv + (float)r8[i]);
                    val[i + 4] = (bf16_t)(f1[i] * inv + (float)r8[i + 4]);
                }
                *(bf16x8*)&C[off] = val;
            }
        }
        return;
    }

    const int seg = (EPI == 6) ? (ntile >> 10) : 0;
    const float* bp = bias;
    if constexpr (EPI == 6) bp = (seg == 0) ? bias : (seg == 1) ? aux_f : bias3;

    // stage 1: registers -> LDS bf16 (col-chunk XOR row&7 swizzle)
    #pragma unroll
    for (int fm = 0; fm < 8; ++fm) {
        #pragma unroll
        for (int reg = 0; reg < 4; ++reg) {
            const int rl = wrow + fm * 16 + lq * 4 + reg;        // 0..255
            #pragma unroll
            for (int fn = 0; fn < 4; ++fn) {
                const int cl = wcol + fn * 16 + lr;              // 0..255
                float v = acc[fm][fn][reg];
                if constexpr (EPI == 0)
                    v += bias[ntile + cl] + aux_f[((mtile + rl) & (SEQ-1))*DMODEL + ntile + cl];
                if constexpr (EPI == 3) v = __expf(v * 0.03125f);  // exp(s/sqrt(D))
                if constexpr (EPI == 6) v += bp[(ntile + cl) & 1023];
                smem[rl * 256 + ((((cl >> 3) ^ (rl & 7)) << 3) | (cl & 7))] = (bf16_t)v;
            }
        }
    }
    __syncthreads();

    // stage 2: LDS -> global, coalesced
    if constexpr (EPI == 3) {
        bf16_t* C = Cb + (long)z * batchC;
        float* rsum = logits + (long)z * SEQ;          // rowsum passed via logits
        const int chunk = tid & 31;
        const int grp   = tid >> 5;
        #pragma unroll
        for (int rep = 0; rep < 16; ++rep) {
            const int R = grp + (rep << 4);
            const int phys = chunk ^ (R & 7);
            bf16x8 val = *(const bf16x8*)&smem[R * 256 + (phys << 3)];
            const long off = (long)(mtile + R) * ldc + ntile + (chunk << 3);
            *(bf16x8*)&C[off] = val;
            float ps = 0.f;
            #pragma unroll
            for (int i = 0; i < 8; ++i) ps += (float)val[i];
            ps += __shfl_xor(ps, 1);
            ps += __shfl_xor(ps, 2);
            ps += __shfl_xor(ps, 4);
            ps += __shfl_xor(ps, 8);
            ps += __shfl_xor(ps, 16);
            if (chunk == 0) atomicAdd(&rsum[mtile + R], ps);
        }
        return;
    }

    if constexpr (EPI == 6) {
        if (seg == 2) {
            // V transposed: VT[b][n][s]; contiguous dim = s = m
            bf16_t* VTb = Cb + 33554432;                     // Qb + 32M elems
            const int col  = tid & 255;                      // n_local within tile
            const int half = tid >> 8;
            const int b    = mtile >> 11, s0 = mtile & (SEQ-1);
            const long nbase = (long)b*DMODEL + (ntile & 1023) + col;
            #pragma unroll
            for (int rep = 0; rep < 16; ++rep) {
                const int R0 = half * 128 + rep * 8;
                bf16x8 o;
                #pragma unroll
                for (int i = 0; i < 8; ++i) {
                    const int rl = R0 + i;
                    o[i] = smem[rl * 256 + ((((col >> 3) ^ (rl & 7)) << 3) | (col & 7))];
                }
                *(bf16x8*)&VTb[nbase * SEQ + s0 + R0] = o;
            }
            return;
        }
        const int chunk = tid & 31;
        const int grp   = tid >> 5;
        const long base = (long)seg * 16777216 + (ntile & 1023) + (chunk << 3);
        #pragma unroll
        for (int rep = 0; rep < 16; ++rep) {
            const int R = grp + (rep << 4);
            const int phys = chunk ^ (R & 7);
            bf16x8 val = *(const bf16x8*)&smem[R * 256 + (phys << 3)];
            *(bf16x8*)&Cb[base + (long)(mtile + R) * 1024] = val;
        }
        return;
    }

    bf16_t* C = Cb + (long)z * batchC;
    const int chunk = tid & 31;
    const int grp   = tid >> 5;
    #pragma unroll
    for (int rep = 0; rep < 16; ++rep) {
        const int R = grp + (rep << 4);
        const int phys = chunk ^ (R & 7);
        bf16x8 val = *(const bf16x8*)&smem[R * 256 + (phys << 3)];
        const long off = (long)(mtile + R) * ldc + ntile + (chunk << 3);
        *(bf16x8*)&C[off] = val;
    }
}

// ---------------------------------------------------------------------------
// All fp32->bf16 casts + logits/rowsum zeroing in ONE launch.
__global__ __launch_bounds__(256) void cast_all(
        const float* __restrict__ inp, const float* __restrict__ emw,
        const float* __restrict__ wqw, const float* __restrict__ wkw,
        const float* __restrict__ wvw, const float* __restrict__ skw,
        bf16_t* __restrict__ in_b, bf16_t* __restrict__ we_b,
        bf16_t* __restrict__ wq_b, bf16_t* __restrict__ wk_b,
        bf16_t* __restrict__ wv_b, bf16_t* __restrict__ sk_b,
        float* __restrict__ logits, float* __restrict__ rowsum) {
    const int i = blockIdx.x*256 + threadIdx.x;
    const float* s; bf16_t* d; int j;
    if      (i < 2097152) { s = inp; d = in_b; j = i; }
    else if (i < 2228224) { s = emw; d = we_b; j = i - 2097152; }
    else if (i < 2490368) { s = wqw; d = wq_b; j = i - 2228224; }
    else if (i < 2752512) { s = wkw; d = wk_b; j = i - 2490368; }
    else if (i < 3014656) { s = wvw; d = wv_b; j = i - 2752512; }
    else if (i < 3276800) { s = skw; d = sk_b; j = i - 3014656; }
    else if (i < 3280896) { ((f32x4*)logits)[i - 3276800] = (f32x4)(0.f); return; }
    else                  { ((f32x4*)rowsum)[i - 3280896] = (f32x4)(0.f); return; }
    const float4 f = ((const float4*)s)[j];
    bf16x4 o;
    o[0] = (bf16_t)f.x; o[1] = (bf16_t)f.y; o[2] = (bf16_t)f.z; o[3] = (bf16_t)f.w;
    ((bf16x4*)d)[j] = o;
}

// LayerNorm over 1024: one block per row, h bf16 -> H bf16 (vectorized)
__global__ __launch_bounds__(256) void layernorm_k(const bf16_t* __restrict__ h, bf16_t* __restrict__ H,
                                                   const float* __restrict__ gam, const float* __restrict__ bet) {
    const long row = blockIdx.x;
    const bf16_t* hr = h + row*DMODEL;
    bf16_t* Hr = H + row*DMODEL;
    const int t = threadIdx.x, lane = t & 63, wave = t >> 6;
    __shared__ float sm[8];
    const bf16x4 hv = *(const bf16x4*)&hr[t*4];
    float v[4]; float s = 0.f, q = 0.f;
    #pragma unroll
    for (int j = 0; j < 4; ++j) { v[j] = (float)hv[j]; s += v[j]; q += v[j]*v[j]; }
    #pragma unroll
    for (int o = 32; o; o >>= 1) { s += __shfl_xor(s, o); q += __shfl_xor(q, o); }
    if (lane == 0) { sm[wave] = s; sm[4 + wave] = q; }
    __syncthreads();
    s = (sm[0] + sm[1]) + (sm[2] + sm[3]);
    q = (sm[4] + sm[5]) + (sm[6] + sm[7]);
    const float mu  = s * (1.f/DMODEL);
    const float var = q * (1.f/DMODEL) - mu*mu;
    const float r   = rsqrtf(var + 1e-5f);
    const float4 g4 = ((const float4*)gam)[t];
    const float4 b4 = ((const float4*)bet)[t];
    bf16x4 o4;
    o4[0] = (bf16_t)((v[0] - mu)*r*g4.x + b4.x);
    o4[1] = (bf16_t)((v[1] - mu)*r*g4.y + b4.y);
    o4[2] = (bf16_t)((v[2] - mu)*r*g4.z + b4.z);
    o4[3] = (bf16_t)((v[3] - mu)*r*g4.w + b4.w);
    *(bf16x4*)&Hr[t*4] = o4;
}

// ---------------------------------------------------------------------------
// Pooling stage 1 with fused per-batch logit softmax.
__global__ __launch_bounds__(256) void pool_partial(const float* __restrict__ logits,
                                                    const bf16_t* __restrict__ H,
                                                    float* __restrict__ part) {
    const int b = blockIdx.y;
    const int c = blockIdx.x;
    const int t = threadIdx.x, lane = t & 63, wave = t >> 6;
    __shared__ float sm[8];
    __shared__ float wsm[32];
    const float* lb = logits + b*SEQ;
    const float4 a4 = ((const float4*)lb)[t];
    const float4 c4 = ((const float4*)lb)[t + 256];
    float v[8] = {a4.x, a4.y, a4.z, a4.w, c4.x, c4.y, c4.z, c4.w};
    float mx = -3.0e38f;
    #pragma unroll
    for (int j = 0; j < 8; ++j) mx = fmaxf(mx, v[j]);
    #pragma unroll
    for (int o = 32; o; o >>= 1) mx = fmaxf(mx, __shfl_xor(mx, o));
    if (lane == 0) sm[wave] = mx;
    __syncthreads();
    mx = fmaxf(fmaxf(sm[0], sm[1]), fmaxf(sm[2], sm[3]));
    float s = 0.f;
    #pragma unroll
    for (int j = 0; j < 8; ++j) s += __expf(v[j] - mx);
    #pragma unroll
    for (int o = 32; o; o >>= 1) s += __shfl_xor(s, o);
    if (lane == 0) sm[4 + wave] = s;
    __syncthreads();
    s = (sm[4] + sm[5]) + (sm[6] + sm[7]);
    const float inv = 1.f / s;
    if (t < 32) wsm[t] = __expf(lb[c*32 + t] - mx) * inv;
    __syncthreads();

    const bf16_t* Hb = H + ((long)b*SEQ + (long)c*32)*DMODEL;
    f32x4 acc = (f32x4)(0.f);
    #pragma unroll 4
    for (int i = 0; i < 32; ++i) {
        const float wi = wsm[i];
        const bf16x4 hv = *(const bf16x4*)&Hb[(long)i*DMODEL + t*4];
        acc[0] += wi * (float)hv[0];
        acc[1] += wi * (float)hv[1];
        acc[2] += wi * (float)hv[2];
        acc[3] += wi * (float)hv[3];
    }
    *(f32x4*)&part[((long)b*64 + c)*DMODEL + t*4] = acc;
}

// stage 2: out[b][o] = sum_c part[b][c][o]; 8192 threads
__global__ __launch_bounds__(256) void pool_reduce(const float* __restrict__ part,
                                                   float* __restrict__ out) {
    const int i = blockIdx.x*256 + threadIdx.x;   // 0..8191
    const int b = i >> 10, o = i & 1023;
    const float* p = part + (long)b*64*DMODEL + o;
    float s = 0.f;
    #pragma unroll
    for (int c = 0; c < 64; ++c) s += p[c*DMODEL];
    out[i] = s;
}

// ---------------------------------------------------------------------------
extern "C" void kernel_launch(void* const* d_in, const int* in_sizes, int n_in,
                              void* d_out, int out_size, void* d_ws, size_t ws_size,
                              hipStream_t stream) {
    (void)in_sizes; (void)n_in; (void)out_size; (void)ws_size;
    const float* inp = (const float*)d_in[0];
    const float* emw = (const float*)d_in[1];
    const float* emb = (const float*)d_in[2];
    const float* wqw = (const float*)d_in[3];
    const float* wqb = (const float*)d_in[4];
    const float* wkw = (const float*)d_in[5];
    const float* wkb = (const float*)d_in[6];
    const float* wvw = (const float*)d_in[7];
    const float* wvb = (const float*)d_in[8];
    const float* lng = (const float*)d_in[9];
    const float* lnb = (const float*)d_in[10];
    const float* skw = (const float*)d_in[11];
    const float* sq  = (const float*)d_in[12];
    const float* pos = (const float*)d_in[13];
    float* out = (float*)d_out;

    char* ws = (char*)d_ws;
    bf16_t* in_b   = (bf16_t*)(ws + 0);            // 16 MB (dead after embed; reused by pool partials)
    bf16_t* we_b   = (bf16_t*)(ws + 16777216);     // 1 MB
    bf16_t* wq_b   = (bf16_t*)(ws + 17825792);     // 2 MB  } contiguous [3072][1024]
    bf16_t* wk_b   = (bf16_t*)(ws + 19922944);     // 2 MB  }
    bf16_t* wv_b   = (bf16_t*)(ws + 22020096);     // 2 MB  }
    bf16_t* sk_b   = (bf16_t*)(ws + 24117248);     // 2 MB
    float*  logits = (float*)(ws + 26214400);      // 64 KB
    float*  rowsum = (float*)(ws + 26279936);      // 64 KB (softmax denominators)
    bf16_t* xb     = (bf16_t*)(ws + 26345472);     // 32 MB  x (bf16)
    bf16_t* Qb     = (bf16_t*)(ws + 59899904);     // 32 MB  Q, later h   } Q|K|VT contiguous
    bf16_t* Kb     = (bf16_t*)(ws + 93454336);     // 32 MB               }
    bf16_t* VT     = (bf16_t*)(ws + 127008768);    // 32 MB  V^T [b][1024][2048]
    bf16_t* Hb     = (bf16_t*)(ws + 160563200);    // 32 MB
    bf16_t* Pb     = (bf16_t*)(ws + 194117632);    // 64 MB  P' = exp(scores)
    float*  part   = (float*)(ws + 0);             // 2 MB pool partials (aliases dead in_b)

    // all casts + logits/rowsum zero, one launch
    cast_all<<<12832, 256, 0, stream>>>(inp, emw, wqw, wkw, wvw, skw,
                                        in_b, we_b, wq_b, wk_b, wv_b, sk_b,
                                        logits, rowsum);

    // x = inputs @ embed_w^T + bias + pos       (gx=4 n-tiles, gy=64 m-tiles)
    gemm_bt<0><<<256, 512, 0, stream>>>(in_b, we_b, xb, D_IN, DMODEL, 4, 64,
        0, 0, 0, emb, pos, nullptr, nullptr, nullptr);
    // fused QKV: N=3072 over contiguous weights; writes Q | K | VT
    gemm_bt<6><<<768, 512, 0, stream>>>(xb, wq_b, Qb, DMODEL, DMODEL, 12, 64,
        0, 0, 0, wqb, wkb, nullptr, nullptr, wvb);
    // P' = exp(Q K^T / 32) per batch + rowsum atomics   (one batch per XCD)
    gemm_bt<3><<<512, 512, 0, stream>>>(Qb, Kb, Pb, DMODEL, SEQ, 8, 8,
        (long)SEQ*DMODEL, (long)SEQ*DMODEL, (long)SEQ*SEQ, nullptr, nullptr, nullptr, rowsum, nullptr);
    // h = (P' V)/rowsum + x  (written over Q buffer)
    gemm_bt<4><<<256, 512, 0, stream>>>(Pb, VT, Qb, SEQ, DMODEL, 4, 8,
        (long)SEQ*SEQ, (long)DMODEL*SEQ, (long)SEQ*DMODEL, rowsum, nullptr, xb, nullptr, nullptr);
    layernorm_k<<<NTOK, 256, 0, stream>>>(Qb, Hb, lng, lnb);
    // logits[m] = sum_n tanh(H skw^T) * soft_query[n]
    gemm_bt<5><<<256, 512, 0, stream>>>(Hb, sk_b, nullptr, DMODEL, 0, 4, 64,
        0, 0, 0, nullptr, sq, nullptr, logits, nullptr);
    // pooled output: fused softmax + two-stage parallel reduction
    pool_partial<<<dim3(64, BATCH), 256, 0, stream>>>(logits, Hb, part);
    pool_reduce<<<32, 256, 0, stream>>>(part, out);
}